// Round 7
// baseline (345.979 us; speedup 1.0000x reference)
//
#include <hip/hip_runtime.h>
#include <math.h>

#define NF 64

// ---------------------------------------------------------------------------
// Composite matrices: the ENTIRE network between x and the two aggregations
// collapses to one [64 x 8] matrix. Layout: comp[k*8 + {0..7}] =
//   Mp[k].{0,1}, Np[k].{0,1}, Mq[k].{0,1}, Nq[k].{0,1}
// where Mp = Wl1^T@Wl2^T (mean path -> p), Np = Wr1^T@Wl2^T (self -> p),
//       Mq = Wl1^T@Wr2^T (mean -> q),      Nq = Wr1^T@Wr2^T (self -> q).
// comp[512..515] = bl1@Wl2^T (cp0,cp1), bl1@Wr2^T (cq0,cq1).
// ---------------------------------------------------------------------------
__global__ __launch_bounds__(256) void k_compose(
    const float* __restrict__ Wl1, const float* __restrict__ bl1,
    const float* __restrict__ Wr1, const float* __restrict__ Wl2,
    const float* __restrict__ Wr2, float* __restrict__ comp) {
    int t = threadIdx.x;
    int m = t >> 6;          // 0:Mp 1:Np 2:Mq 3:Nq
    int k = t & 63;
    const float* W1 = (m == 0 || m == 2) ? Wl1 : Wr1;
    const float* W2 = (m < 2) ? Wl2 : Wr2;
    float a0 = 0.f, a1 = 0.f;
    for (int o = 0; o < NF; ++o) {
        float w1 = W1[o * NF + k];
        a0 = fmaf(W2[o], w1, a0);
        a1 = fmaf(W2[NF + o], w1, a1);
    }
    comp[k * 8 + 2 * m]     = a0;
    comp[k * 8 + 2 * m + 1] = a1;
    if (t < 4) {
        const float* W2c = (t < 2) ? Wl2 : Wr2;
        int c = t & 1;
        float s = 0.f;
        for (int o = 0; o < NF; ++o) s = fmaf(bl1[o], W2c[c * NF + o], s);
        comp[512 + t] = s;
    }
}

// ---------------------------------------------------------------------------
// Project every node through the composites: Y = x @ [Mp|Np|Mq|Nq].
// ac[node] = (a0,a1,c0,c1)  -> the ONLY thing edges ever touch (1.6 MB,
//                              fits a single XCD's 4 MiB L2).
// bd[node] = (b0+cp0, b1+cp1, d0+cq0, d1+cq1)  -> self terms + bias consts.
// Thread per node; comp loads are wave-uniform (scalar); x rows stream
// through L1 (64 rows x 256 B = 16 KB working set per wave).
// ---------------------------------------------------------------------------
__global__ __launch_bounds__(256) void k_project(
    const float4* __restrict__ x4, const float* __restrict__ comp,
    float4* __restrict__ ac, float4* __restrict__ bd, int N) {
    int node = blockIdx.x * 256 + threadIdx.x;
    if (node >= N) return;
    float a0 = 0.f, a1 = 0.f, b0 = 0.f, b1 = 0.f;
    float c0 = 0.f, c1 = 0.f, d0 = 0.f, d1 = 0.f;
#pragma unroll
    for (int kk = 0; kk < 16; ++kk) {
        float4 xv = x4[(size_t)node * 16 + kk];
        const float xs[4] = {xv.x, xv.y, xv.z, xv.w};
#pragma unroll
        for (int j = 0; j < 4; ++j) {
            float xj = xs[j];
            const float* c8 = comp + (kk * 4 + j) * 8;
            a0 = fmaf(xj, c8[0], a0); a1 = fmaf(xj, c8[1], a1);
            b0 = fmaf(xj, c8[2], b0); b1 = fmaf(xj, c8[3], b1);
            c0 = fmaf(xj, c8[4], c0); c1 = fmaf(xj, c8[5], c1);
            d0 = fmaf(xj, c8[6], d0); d1 = fmaf(xj, c8[7], d1);
        }
    }
    ac[node] = make_float4(a0, a1, c0, c1);
    bd[node] = make_float4(b0 + comp[512], b1 + comp[513],
                           d0 + comp[514], d1 + comp[515]);
}

// ---------------------------------------------------------------------------
// Layer-1 aggregation: acc[dst] += ac[src] (4 floats) + deg histogram.
// Lane layout (edge,component): 4 consecutive lanes hit 4 consecutive words
// of acc[d] -> same-line atomic merge opportunity at the TCC.
// ---------------------------------------------------------------------------
__global__ __launch_bounds__(256) void k_scatter_ac(
    const int* __restrict__ ei, const float* __restrict__ ac,
    float* __restrict__ acc, float* __restrict__ deg, int E) {
    int t = blockIdx.x * 256 + threadIdx.x;
    int e = t >> 2, c = t & 3;
    if (e >= E) return;
    int s = ei[e];
    int d = ei[E + e];
    atomicAdd(&acc[(size_t)d * 4 + c], ac[(size_t)s * 4 + c]);
    if (c == 0) atomicAdd(&deg[d], 1.0f);
}

// ---------------------------------------------------------------------------
// Combine: p = acc.ab/deg + bd.ab ; q = acc.cd/deg + bd.cd. Thread per node.
// ---------------------------------------------------------------------------
__global__ __launch_bounds__(256) void k_combine(
    const float4* __restrict__ acc, const float* __restrict__ deg,
    const float4* __restrict__ bd, float2* __restrict__ p,
    float2* __restrict__ q, int N) {
    int node = blockIdx.x * 256 + threadIdx.x;
    if (node >= N) return;
    float4 s = acc[node];
    float4 b = bd[node];
    float dgf = fmaxf(deg[node], 1.f);
    float inv = 1.f / dgf;
    p[node] = make_float2(fmaf(s.x, inv, b.x), fmaf(s.y, inv, b.y));
    q[node] = make_float2(fmaf(s.z, inv, b.z), fmaf(s.w, inv, b.w));
}

// ---------------------------------------------------------------------------
// Layer-2 aggregation: agg2[dst] += p[src] (2 floats). p is 800 KB ->
// L2-resident reads; (edge,component) lane layout as above.
// ---------------------------------------------------------------------------
__global__ __launch_bounds__(256) void k_scatter_p(
    const int* __restrict__ ei, const float* __restrict__ p,
    float* __restrict__ agg2, int E) {
    int t = blockIdx.x * 256 + threadIdx.x;
    int e = t >> 1, c = t & 1;
    if (e >= E) return;
    int s = ei[e];
    int d = ei[E + e];
    atomicAdd(&agg2[(size_t)d * 2 + c], p[(size_t)s * 2 + c]);
}

// ---------------------------------------------------------------------------
// Final: logits = agg2/deg + bl2 + q ; out = log_softmax. Thread per node.
// ---------------------------------------------------------------------------
__global__ __launch_bounds__(256) void k_final(
    const float2* __restrict__ agg2, const float* __restrict__ deg,
    const float2* __restrict__ q, const float* __restrict__ bl2,
    float2* __restrict__ out, int N) {
    int node = blockIdx.x * 256 + threadIdx.x;
    if (node >= N) return;
    float2 a2 = agg2[node];
    float2 qv = q[node];
    float inv = 1.f / fmaxf(deg[node], 1.f);
    float l0 = fmaf(a2.x, inv, bl2[0] + qv.x);
    float l1 = fmaf(a2.y, inv, bl2[1] + qv.y);
    float m = fmaxf(l0, l1);
    float lse = m + logf(expf(l0 - m) + expf(l1 - m));
    out[node] = make_float2(l0 - lse, l1 - lse);
}

// ---------------------------------------------------------------------------
extern "C" void kernel_launch(void* const* d_in, const int* in_sizes, int n_in,
                              void* d_out, int out_size, void* d_ws, size_t ws_size,
                              hipStream_t stream) {
    const float* x   = (const float*)d_in[0];
    const int*   ei  = (const int*)d_in[1];
    const float* Wl1 = (const float*)d_in[2];
    const float* bl1 = (const float*)d_in[3];
    const float* Wr1 = (const float*)d_in[4];
    const float* Wl2 = (const float*)d_in[5];
    const float* bl2 = (const float*)d_in[6];
    const float* Wr2 = (const float*)d_in[7];
    float* out = (float*)d_out;

    int N = in_sizes[0] / NF;     // 100000
    int E = in_sizes[1] / 2;      // 1600000

    // Workspace (floats):
    // [acc:4N | agg2:2N | deg:N]  <- zeroed (7N = 2.8 MB)
    // [ac:4N | bd:4N | p:2N | q:2N | comp:516]
    float* ws   = (float*)d_ws;
    float* acc  = ws;
    float* agg2 = ws + 4 * (size_t)N;
    float* deg  = ws + 6 * (size_t)N;
    float* ac   = ws + 7 * (size_t)N;
    float* bd   = ac + 4 * (size_t)N;
    float* p    = bd + 4 * (size_t)N;
    float* q    = p + 2 * (size_t)N;
    float* comp = q + 2 * (size_t)N;

    hipMemsetAsync(ws, 0, 7 * (size_t)N * sizeof(float), stream);

    int nbN = (N + 255) / 256;

    k_compose<<<1, 256, 0, stream>>>(Wl1, bl1, Wr1, Wl2, Wr2, comp);
    k_project<<<nbN, 256, 0, stream>>>((const float4*)x, comp,
                                       (float4*)ac, (float4*)bd, N);
    k_scatter_ac<<<(4 * E + 255) / 256, 256, 0, stream>>>(ei, ac, acc, deg, E);
    k_combine<<<nbN, 256, 0, stream>>>((const float4*)acc, deg,
                                       (const float4*)bd,
                                       (float2*)p, (float2*)q, N);
    k_scatter_p<<<(2 * E + 255) / 256, 256, 0, stream>>>(ei, p, agg2, E);
    k_final<<<nbN, 256, 0, stream>>>((const float2*)agg2, deg,
                                     (const float2*)q, bl2,
                                     (float2*)out, N);
}

// Round 8
// 198.927 us; speedup vs baseline: 1.7392x; 1.7392x over previous
//
#include <hip/hip_runtime.h>
#include <math.h>

#define NF 64
#define SHIFT 9              // 512 nodes per dst-bucket
#define BSZ 512
#define MAXNB 256            // bucket arrays sized for <=256 buckets
#define CHUNK 4096           // edges per kb_bin block

// ---------------------------------------------------------------------------
// Bucket histogram of dst>>SHIFT (LDS-aggregated).
// ---------------------------------------------------------------------------
__global__ __launch_bounds__(256) void kb_hist(
    const int* __restrict__ ei, int* __restrict__ bhist, int E, int nb) {
    __shared__ int h[MAXNB];
    int t = threadIdx.x;
    if (t < nb) h[t] = 0;
    __syncthreads();
    int stride = gridDim.x * 256;
    for (int e = blockIdx.x * 256 + t; e < E; e += stride)
        atomicAdd(&h[((unsigned)ei[E + e]) >> SHIFT], 1);
    __syncthreads();
    if (t < nb && h[t]) atomicAdd(&bhist[t], h[t]);
}

// ---------------------------------------------------------------------------
// Exclusive scan of bucket counts -> bbase (+ cursor copy bcur).
// ---------------------------------------------------------------------------
__global__ __launch_bounds__(256) void kb_scan(
    const int* __restrict__ bhist, int* __restrict__ bbase,
    int* __restrict__ bcur, int nb) {
    __shared__ int s[256];
    int t = threadIdx.x;
    int v = (t < nb) ? bhist[t] : 0;
    s[t] = v;
    __syncthreads();
    for (int off = 1; off < 256; off <<= 1) {
        int a = (t >= off) ? s[t - off] : 0;
        __syncthreads();
        s[t] += a;
        __syncthreads();
    }
    if (t < nb) { bbase[t] = s[t] - v; bcur[t] = s[t] - v; }
    if (t == nb - 1) bbase[nb] = s[t];      // total = E
}

// ---------------------------------------------------------------------------
// Bin edges by dst-bucket with in-LDS local sort; flush each bucket's run as
// a CONTIGUOUS global write (avoids line-bounce amplification).
// Packed edge: (d_local<<17)|src  (needs N < 2^17; d_local < 512).
// ---------------------------------------------------------------------------
__global__ __launch_bounds__(256) void kb_bin(
    const int* __restrict__ ei, int* __restrict__ bcur,
    int* __restrict__ ebin, int E, int nb) {
    __shared__ int spair[CHUNK];
    __shared__ unsigned short sbkt[CHUNK];
    __shared__ int h[MAXNB], sb[MAXNB], lcur[MAXNB], goff[MAXNB];
    __shared__ int ss[256];
    int t = threadIdx.x;
    int e0 = blockIdx.x * CHUNK;
    if (t < nb) h[t] = 0;
    __syncthreads();

    int pv[CHUNK / 256], pb[CHUNK / 256];
#pragma unroll
    for (int k = 0; k < CHUNK / 256; ++k) {
        int e = e0 + k * 256 + t;
        if (e < E) {
            int sv = ei[e];
            unsigned d = (unsigned)ei[E + e];
            int b = d >> SHIFT;
            pb[k] = b;
            pv[k] = (int)(((d & (BSZ - 1)) << 17) | (unsigned)sv);
            atomicAdd(&h[b], 1);
        } else pb[k] = -1;
    }
    __syncthreads();
    {   // exclusive scan h -> sb (+ cursor)
        int v = (t < nb) ? h[t] : 0;
        ss[t] = v;
        __syncthreads();
        for (int off = 1; off < 256; off <<= 1) {
            int a = (t >= off) ? ss[t - off] : 0;
            __syncthreads();
            ss[t] += a;
            __syncthreads();
        }
        if (t < nb) { sb[t] = ss[t] - v; lcur[t] = ss[t] - v; }
    }
    __syncthreads();
#pragma unroll
    for (int k = 0; k < CHUNK / 256; ++k) {
        if (pb[k] >= 0) {
            int pos = atomicAdd(&lcur[pb[k]], 1);
            spair[pos] = pv[k];
            sbkt[pos] = (unsigned short)pb[k];
        }
    }
    __syncthreads();
    if (t < nb && h[t] > 0) goff[t] = atomicAdd(&bcur[t], h[t]);
    __syncthreads();
    int M = min(CHUNK, E - e0);
    for (int i = t; i < M; i += 256) {
        int b = sbkt[i];
        ebin[goff[b] + i - sb[b]] = spair[i];
    }
}

// ---------------------------------------------------------------------------
// Composite matrices: whole network between x and the two aggregations
// collapses to one [64 x 8]: comp[k*8+..] = Mp.{01},Np.{01},Mq.{01},Nq.{01};
// comp[512..515] = bl1@Wl2^T, bl1@Wr2^T.
// ---------------------------------------------------------------------------
__global__ __launch_bounds__(256) void k_compose(
    const float* __restrict__ Wl1, const float* __restrict__ bl1,
    const float* __restrict__ Wr1, const float* __restrict__ Wl2,
    const float* __restrict__ Wr2, float* __restrict__ comp) {
    int t = threadIdx.x;
    int m = t >> 6;          // 0:Mp 1:Np 2:Mq 3:Nq
    int k = t & 63;
    const float* W1 = (m == 0 || m == 2) ? Wl1 : Wr1;
    const float* W2 = (m < 2) ? Wl2 : Wr2;
    float a0 = 0.f, a1 = 0.f;
    for (int o = 0; o < NF; ++o) {
        float w1 = W1[o * NF + k];
        a0 = fmaf(W2[o], w1, a0);
        a1 = fmaf(W2[NF + o], w1, a1);
    }
    comp[k * 8 + 2 * m]     = a0;
    comp[k * 8 + 2 * m + 1] = a1;
    if (t < 4) {
        const float* W2c = (t < 2) ? Wl2 : Wr2;
        int c = t & 1;
        float s = 0.f;
        for (int o = 0; o < NF; ++o) s = fmaf(bl1[o], W2c[c * NF + o], s);
        comp[512 + t] = s;
    }
}

// ---------------------------------------------------------------------------
// Project nodes through composites: ac[node]=(a0,a1,c0,c1) is the ONLY thing
// edges touch (1.6 MB -> L2-resident); bd[node]=self terms + bias consts.
// ---------------------------------------------------------------------------
__global__ __launch_bounds__(256) void k_project(
    const float4* __restrict__ x4, const float* __restrict__ comp,
    float4* __restrict__ ac, float4* __restrict__ bd, int N) {
    int node = blockIdx.x * 256 + threadIdx.x;
    if (node >= N) return;
    float a0 = 0.f, a1 = 0.f, b0 = 0.f, b1 = 0.f;
    float c0 = 0.f, c1 = 0.f, d0 = 0.f, d1 = 0.f;
#pragma unroll
    for (int kk = 0; kk < 16; ++kk) {
        float4 xv = x4[(size_t)node * 16 + kk];
        const float xs[4] = {xv.x, xv.y, xv.z, xv.w};
#pragma unroll
        for (int j = 0; j < 4; ++j) {
            float xj = xs[j];
            const float* c8 = comp + (kk * 4 + j) * 8;
            a0 = fmaf(xj, c8[0], a0); a1 = fmaf(xj, c8[1], a1);
            b0 = fmaf(xj, c8[2], b0); b1 = fmaf(xj, c8[3], b1);
            c0 = fmaf(xj, c8[4], c0); c1 = fmaf(xj, c8[5], c1);
            d0 = fmaf(xj, c8[6], d0); d1 = fmaf(xj, c8[7], d1);
        }
    }
    ac[node] = make_float4(a0, a1, c0, c1);
    bd[node] = make_float4(b0 + comp[512], b1 + comp[513],
                           d0 + comp[514], d1 + comp[515]);
}

// ---------------------------------------------------------------------------
// Layer-1 aggregation, one block per bucket: accumulate ac[src] into LDS
// acc[512][4] (+ integer deg), then finalize p,q,deg in-block.
// No global atomics anywhere.
// ---------------------------------------------------------------------------
__global__ __launch_bounds__(1024) void k_agg1(
    const int* __restrict__ ebin, const int* __restrict__ bbase,
    const float4* __restrict__ ac, const float4* __restrict__ bd,
    float2* __restrict__ p, float2* __restrict__ q,
    float* __restrict__ deg, int N) {
    __shared__ float acc[BSZ][4];
    __shared__ int ldeg[BSZ];
    int b = blockIdx.x, t = threadIdx.x;
    if (t < BSZ) {
        acc[t][0] = 0.f; acc[t][1] = 0.f; acc[t][2] = 0.f; acc[t][3] = 0.f;
        ldeg[t] = 0;
    }
    __syncthreads();
    int g0 = bbase[b], g1 = bbase[b + 1];
    for (int i = g0 + t; i < g1; i += 1024) {
        int pv = ebin[i];
        int dl = pv >> 17;
        float4 v = ac[pv & 0x1FFFF];
        atomicAdd(&acc[dl][0], v.x);
        atomicAdd(&acc[dl][1], v.y);
        atomicAdd(&acc[dl][2], v.z);
        atomicAdd(&acc[dl][3], v.w);
        atomicAdd(&ldeg[dl], 1);
    }
    __syncthreads();
    int node = (b << SHIFT) + t;
    if (t < BSZ && node < N) {
        float dg = (float)(ldeg[t] > 1 ? ldeg[t] : 1);
        float inv = 1.f / dg;
        float4 bdv = bd[node];
        p[node] = make_float2(fmaf(acc[t][0], inv, bdv.x),
                              fmaf(acc[t][1], inv, bdv.y));
        q[node] = make_float2(fmaf(acc[t][2], inv, bdv.z),
                              fmaf(acc[t][3], inv, bdv.w));
        deg[node] = dg;
    }
}

// ---------------------------------------------------------------------------
// Layer-2 aggregation + epilogue, one block per bucket: accumulate p[src]
// into LDS, then logits = agg2/deg + bl2 + q; out = log_softmax. Fused final.
// ---------------------------------------------------------------------------
__global__ __launch_bounds__(1024) void k_agg2(
    const int* __restrict__ ebin, const int* __restrict__ bbase,
    const float2* __restrict__ p, const float2* __restrict__ q,
    const float* __restrict__ deg, const float* __restrict__ bl2,
    float2* __restrict__ out, int N) {
    __shared__ float a2[BSZ][2];
    int b = blockIdx.x, t = threadIdx.x;
    if (t < BSZ) { a2[t][0] = 0.f; a2[t][1] = 0.f; }
    __syncthreads();
    int g0 = bbase[b], g1 = bbase[b + 1];
    for (int i = g0 + t; i < g1; i += 1024) {
        int pv = ebin[i];
        int dl = pv >> 17;
        float2 v = p[pv & 0x1FFFF];
        atomicAdd(&a2[dl][0], v.x);
        atomicAdd(&a2[dl][1], v.y);
    }
    __syncthreads();
    int node = (b << SHIFT) + t;
    if (t < BSZ && node < N) {
        float inv = 1.f / deg[node];
        float2 qv = q[node];
        float l0 = fmaf(a2[t][0], inv, bl2[0] + qv.x);
        float l1 = fmaf(a2[t][1], inv, bl2[1] + qv.y);
        float m = fmaxf(l0, l1);
        float lse = m + logf(expf(l0 - m) + expf(l1 - m));
        out[node] = make_float2(l0 - lse, l1 - lse);
    }
}

// ---------------------------------------------------------------------------
extern "C" void kernel_launch(void* const* d_in, const int* in_sizes, int n_in,
                              void* d_out, int out_size, void* d_ws, size_t ws_size,
                              hipStream_t stream) {
    const float* x   = (const float*)d_in[0];
    const int*   ei  = (const int*)d_in[1];
    const float* Wl1 = (const float*)d_in[2];
    const float* bl1 = (const float*)d_in[3];
    const float* Wr1 = (const float*)d_in[4];
    const float* Wl2 = (const float*)d_in[5];
    const float* bl2 = (const float*)d_in[6];
    const float* Wr2 = (const float*)d_in[7];
    float* out = (float*)d_out;

    int N = in_sizes[0] / NF;     // 100000 (< 2^17 required by packing)
    int E = in_sizes[1] / 2;      // 1600000
    int nb = (N + BSZ - 1) >> SHIFT;   // 196 buckets

    // Workspace: ints [ebin:E | bhist:MAXNB | bbase:MAXNB+1 | bcur:MAXNB]
    //            floats [comp:516 | ac:4N | bd:4N | p:2N | q:2N | deg:N]
    int* wsi    = (int*)d_ws;
    int* ebin   = wsi;
    int* bhist  = wsi + E;
    int* bbase  = bhist + MAXNB;
    int* bcur   = bbase + MAXNB + 1;
    float* comp = (float*)(bcur + MAXNB);
    float* ac   = comp + 516;
    float* bd   = ac + 4 * (size_t)N;
    float* p    = bd + 4 * (size_t)N;
    float* q    = p + 2 * (size_t)N;
    float* deg  = q + 2 * (size_t)N;

    hipMemsetAsync(bhist, 0, MAXNB * sizeof(int), stream);

    int nbN = (N + 255) / 256;

    kb_hist<<<256, 256, 0, stream>>>(ei, bhist, E, nb);
    kb_scan<<<1, 256, 0, stream>>>(bhist, bbase, bcur, nb);
    kb_bin <<<(E + CHUNK - 1) / CHUNK, 256, 0, stream>>>(ei, bcur, ebin, E, nb);

    k_compose<<<1, 256, 0, stream>>>(Wl1, bl1, Wr1, Wl2, Wr2, comp);
    k_project<<<nbN, 256, 0, stream>>>((const float4*)x, comp,
                                       (float4*)ac, (float4*)bd, N);

    k_agg1<<<nb, 1024, 0, stream>>>(ebin, bbase, (const float4*)ac,
                                    (const float4*)bd, (float2*)p,
                                    (float2*)q, deg, N);
    k_agg2<<<nb, 1024, 0, stream>>>(ebin, bbase, (const float2*)p,
                                    (const float2*)q, deg, bl2,
                                    (float2*)out, N);
}